// Round 3
// baseline (109.236 us; speedup 1.0000x reference)
//
#include <hip/hip_runtime.h>
#include <hip/hip_cooperative_groups.h>

namespace cg = cooperative_groups;

// Problem constants (reference: B=4, N=512, F_IN=F_OUT=128)
constexpr int B_   = 4;
constexpr int N_   = 512;
constexpr int F    = 128;
constexpr int R    = 4;     // rows per block
constexpr int LSTW = 520;   // neighbor-list stride (512 + pad)

// ---------------------------------------------------------------------------
// Fused cooperative kernel. 512 blocks x 256 threads (2 blocks/CU).
// Thread (h,o): h = K-half, o = output column. Wave w owns row w in phase A1.
//
// A1: ballot-compaction of this block's 4 adj rows (depends only on adj)
// A2: xi = x@Wi + b_msg (-> LDS), xj = x@Wj (-> ws), xu = x@Wupd[0:F] (-> LDS)
// --- grid.sync ---
// B1: agg[r][o] = sum_{j in lst[r]} relu(xi[r][o] + xj[j][o])
// B2: out = relu(xu + agg@Wupd[F:2F] + b_upd)
// ---------------------------------------------------------------------------
__global__ __launch_bounds__(256, 2) void k_fused(
    const float* __restrict__ x,
    const float* __restrict__ adj,
    const float* __restrict__ Wmsg,
    const float* __restrict__ bmsg,
    const float* __restrict__ Wupd,
    const float* __restrict__ bupd,
    float* __restrict__ xj,
    float* __restrict__ out)
{
    __shared__ __align__(16) float xs[R][F];
    __shared__ __align__(16) int   lst[R][LSTW];
    __shared__ int   cnt[R], cntp[R];
    __shared__ float xiL[R][F];
    __shared__ float aggL[R][F];
    __shared__ float psA[2][R][F];
    __shared__ float psB[2][R][F];
    __shared__ float psU[2][R][F];

    const int t    = threadIdx.x;
    const int lane = t & 63;
    const int w    = t >> 6;             // wave id (row for compaction)
    const int h    = t >> 7;             // K-half
    const int o    = t & 127;            // output column
    const int r0   = blockIdx.x * R;     // global row base (never straddles batch)
    const int b    = r0 >> 9;            // batch
    const int i0   = r0 & (N_ - 1);      // row within batch

    // x rows -> LDS
    for (int idx = t; idx < R * F; idx += 256)
        xs[idx >> 7][idx & 127] = x[(size_t)r0 * F + idx];

    // ---- A1: ballot compaction, wave w owns row w (ascending j, no atomics)
    {
        const float* arow = adj + ((size_t)b * N_ + i0 + w) * N_;
        float a[8];
        #pragma unroll
        for (int s = 0; s < 8; ++s) a[s] = arow[s * 64 + lane];
        int base = 0;
        #pragma unroll
        for (int s = 0; s < 8; ++s) {
            const unsigned long long m = __ballot(a[s] != 0.f);
            const int off = __popcll(m & ((1ull << lane) - 1ull));
            if (a[s] != 0.f) lst[w][base + off] = s * 64 + lane;
            base += __popcll(m);
        }
        const int np = (base + 7) & ~7;
        if (lane < np - base) lst[w][base + lane] = 0;   // pad (predicated off)
        if (lane == 0) { cnt[w] = base; cntp[w] = np; }
    }
    __syncthreads();

    // ---- A2: triple GEMM over this half's 64 k's
    float ai[R] = {0,0,0,0}, aj[R] = {0,0,0,0}, au[R] = {0,0,0,0};
    const int kb = h * 64;
    #pragma unroll
    for (int k = 0; k < 64; k += 4) {
        float4 xv[R];
        #pragma unroll
        for (int r = 0; r < R; ++r)
            xv[r] = *reinterpret_cast<const float4*>(&xs[r][kb + k]);
        #pragma unroll
        for (int u = 0; u < 4; ++u) {
            const int kk = kb + k + u;
            const float wi = Wmsg[(size_t)kk * F + o];
            const float wj = Wmsg[(size_t)(F + kk) * F + o];
            const float wu = Wupd[(size_t)kk * F + o];
            #pragma unroll
            for (int r = 0; r < R; ++r) {
                const float xk = reinterpret_cast<const float*>(&xv[r])[u];
                ai[r] = fmaf(xk, wi, ai[r]);
                aj[r] = fmaf(xk, wj, aj[r]);
                au[r] = fmaf(xk, wu, au[r]);
            }
        }
    }
    #pragma unroll
    for (int r = 0; r < R; ++r) {
        psA[h][r][o] = ai[r]; psB[h][r][o] = aj[r]; psU[h][r][o] = au[r];
    }
    __syncthreads();

    if (h == 0) {
        const float bm = bmsg[o];
        #pragma unroll
        for (int r = 0; r < R; ++r) {
            xiL[r][o] = psA[0][r][o] + psA[1][r][o] + bm;
            xj[(size_t)(r0 + r) * F + o] = psB[0][r][o] + psB[1][r][o];
        }
    }

    __threadfence();           // device-scope: xj visible across XCDs
    cg::this_grid().sync();

    // ---- B1: sparse gather-aggregate (xj rows are L2-resident now)
    const float* xjb = xj + (size_t)b * N_ * F;
    #pragma unroll
    for (int r = 0; r < R; ++r) {
        const float xir = xiL[r][o];
        const int nn = cnt[r], np = cntp[r];
        float acc = 0.f;
        for (int k = h * 4; k < np; k += 8) {
            const int4 id4 = *reinterpret_cast<const int4*>(&lst[r][k]);
            const float v0 = xjb[(size_t)id4.x * F + o];
            const float v1 = xjb[(size_t)id4.y * F + o];
            const float v2 = xjb[(size_t)id4.z * F + o];
            const float v3 = xjb[(size_t)id4.w * F + o];
            acc += (k + 0 < nn) ? fmaxf(xir + v0, 0.f) : 0.f;
            acc += (k + 1 < nn) ? fmaxf(xir + v1, 0.f) : 0.f;
            acc += (k + 2 < nn) ? fmaxf(xir + v2, 0.f) : 0.f;
            acc += (k + 3 < nn) ? fmaxf(xir + v3, 0.f) : 0.f;
        }
        psB[h][r][o] = acc;                      // reuse psB for partials
    }
    __syncthreads();
    if (h == 0) {
        #pragma unroll
        for (int r = 0; r < R; ++r)
            aggL[r][o] = psB[0][r][o] + psB[1][r][o];
    }
    __syncthreads();

    // ---- B2: res2 = agg @ Wupd[F:2F], K=128 split across halves
    float res[R] = {0,0,0,0};
    #pragma unroll
    for (int k = 0; k < 64; k += 4) {
        float4 av[R];
        #pragma unroll
        for (int r = 0; r < R; ++r)
            av[r] = *reinterpret_cast<const float4*>(&aggL[r][kb + k]);
        #pragma unroll
        for (int u = 0; u < 4; ++u) {
            const int kk = kb + k + u;
            const float wv = Wupd[(size_t)(F + kk) * F + o];
            #pragma unroll
            for (int r = 0; r < R; ++r)
                res[r] = fmaf(reinterpret_cast<const float*>(&av[r])[u], wv, res[r]);
        }
    }
    #pragma unroll
    for (int r = 0; r < R; ++r) psA[h][r][o] = res[r];   // reuse psA
    __syncthreads();

    if (h == 0) {
        const float bu = bupd[o];
        #pragma unroll
        for (int r = 0; r < R; ++r)
            out[(size_t)(r0 + r) * F + o] =
                fmaxf(psU[0][r][o] + psU[1][r][o] +
                      psA[0][r][o] + psA[1][r][o] + bu, 0.f);
    }
}

// ---------------------------------------------------------------------------
extern "C" void kernel_launch(void* const* d_in, const int* in_sizes, int n_in,
                              void* d_out, int out_size, void* d_ws, size_t ws_size,
                              hipStream_t stream)
{
    const float* x    = (const float*)d_in[0];
    const float* adj  = (const float*)d_in[1];
    const float* Wmsg = (const float*)d_in[2];
    const float* bmsg = (const float*)d_in[3];
    const float* Wupd = (const float*)d_in[4];
    const float* bupd = (const float*)d_in[5];
    float* out = (float*)d_out;
    float* xj  = (float*)d_ws;                   // 2048*128 floats = 1 MB

    void* args[] = {
        (void*)&x, (void*)&adj, (void*)&Wmsg, (void*)&bmsg,
        (void*)&Wupd, (void*)&bupd, (void*)&xj, (void*)&out
    };
    hipLaunchCooperativeKernel((const void*)k_fused,
                               dim3((B_ * N_) / R), dim3(256),
                               args, 0, stream);
}

// Round 4
// 22.001 us; speedup vs baseline: 4.9651x; 4.9651x over previous
//
#include <hip/hip_runtime.h>

// Problem constants (reference: B=4, N=512, F_IN=F_OUT=128)
constexpr int B_   = 4;
constexpr int N_   = 512;
constexpr int F    = 128;
constexpr int R1B  = 8;     // rows per block, kernel 1
constexpr int R2B  = 4;     // rows per block, kernel 2
constexpr int LSTW = 520;   // neighbor-list stride (512 + pad, 16B-multiple)

// ---------------------------------------------------------------------------
// Kernel 1 (256 blocks x 512 threads): per 8 node rows
//   - ballot-compact adj rows -> lstG/cntG (pad entries -> per-batch sentinel)
//   - xi = x@Wi + b_msg ; xj = x@Wj ; xu = x@Wupd[0:F]   (K split 4 ways)
//   - block 0 writes the global sentinel xj row (-1e30 => relu contributes 0)
// ---------------------------------------------------------------------------
__global__ __launch_bounds__(512, 2) void k_pre(
    const float* __restrict__ x,
    const float* __restrict__ adj,
    const float* __restrict__ Wmsg,
    const float* __restrict__ bmsg,
    const float* __restrict__ Wupd,
    float* __restrict__ xi,
    float* __restrict__ xj,
    float* __restrict__ xu,
    int*   __restrict__ lstG,
    int*   __restrict__ cntG)
{
    __shared__ __align__(16) float xs[R1B][F];
    __shared__ __align__(16) int   lst[R1B][LSTW];
    __shared__ int   cntp[R1B];
    __shared__ float ps[4][3 * R1B][F];     // K-quarter partials (49 KB)

    const int t    = threadIdx.x;
    const int lane = t & 63;
    const int w    = t >> 6;            // wave 0..7 (owns row w for compaction)
    const int q    = t >> 7;            // K-quarter 0..3
    const int o    = t & 127;           // output column
    const int r0   = blockIdx.x * R1B;  // never straddles a batch (512%8==0)
    const int b    = r0 >> 9;
    const int i0   = r0 & (N_ - 1);
    const int PADJ = 2 * N_ * B_ / 2 - b * N_;   // = 2048 - b*512 -> sentinel row

    // sentinel row (block 0 only): relu(xi + (-1e30)) == 0
    if (blockIdx.x == 0 && t < F) xj[(size_t)(B_ * N_) * F + t] = -1e30f;

    // x rows -> LDS
    for (int idx = t; idx < R1B * F; idx += 512)
        xs[idx >> 7][idx & 127] = x[(size_t)r0 * F + idx];

    // ---- ballot compaction: wave w owns row w (ascending j, deterministic)
    {
        const float* arow = adj + ((size_t)b * N_ + i0 + w) * N_;
        float a[8];
        #pragma unroll
        for (int s = 0; s < 8; ++s) a[s] = arow[s * 64 + lane];
        int base = 0;
        #pragma unroll
        for (int s = 0; s < 8; ++s) {
            const unsigned long long m = __ballot(a[s] != 0.f);
            const int off = __popcll(m & ((1ull << lane) - 1ull));
            if (a[s] != 0.f) lst[w][base + off] = s * 64 + lane;
            base += __popcll(m);
        }
        const int np = (base + 7) & ~7;
        if (lane < np - base) lst[w][base + lane] = PADJ;  // sentinel pads
        if (lane == 0) cntp[w] = np;
    }
    __syncthreads();

    // ---- copy compacted lists + counts to global (short, coalesced)
    #pragma unroll
    for (int r = 0; r < R1B; ++r)
        for (int k = t; k < cntp[r]; k += 512)
            lstG[(size_t)(r0 + r) * LSTW + k] = lst[r][k];
    if (t < R1B) cntG[r0 + t] = cntp[t];

    // ---- triple GEMM, K-quarter q (32 k's), 8 rows, 3 outputs
    float ai[R1B] = {0,0,0,0,0,0,0,0};
    float aj[R1B] = {0,0,0,0,0,0,0,0};
    float au[R1B] = {0,0,0,0,0,0,0,0};
    const int kb = q * 32;
    #pragma unroll
    for (int k = 0; k < 32; k += 4) {
        float4 xv[R1B];
        #pragma unroll
        for (int r = 0; r < R1B; ++r)
            xv[r] = *reinterpret_cast<const float4*>(&xs[r][kb + k]);
        #pragma unroll
        for (int u = 0; u < 4; ++u) {
            const int kk = kb + k + u;
            const float wi = Wmsg[(size_t)kk * F + o];
            const float wj = Wmsg[(size_t)(F + kk) * F + o];
            const float wu = Wupd[(size_t)kk * F + o];
            #pragma unroll
            for (int r = 0; r < R1B; ++r) {
                const float xk = reinterpret_cast<const float*>(&xv[r])[u];
                ai[r] = fmaf(xk, wi, ai[r]);
                aj[r] = fmaf(xk, wj, aj[r]);
                au[r] = fmaf(xk, wu, au[r]);
            }
        }
    }
    #pragma unroll
    for (int r = 0; r < R1B; ++r) {
        ps[q][r][o]            = ai[r];
        ps[q][R1B + r][o]      = aj[r];
        ps[q][2 * R1B + r][o]  = au[r];
    }
    __syncthreads();

    // ---- combine: q-group handles 6 of the 24 output rows
    const float bm = bmsg[o];
    #pragma unroll
    for (int i = 0; i < 6; ++i) {
        const int v = q * 6 + i;
        float s = ps[0][v][o] + ps[1][v][o] + ps[2][v][o] + ps[3][v][o];
        float* dst = (v < R1B) ? xi : (v < 2 * R1B) ? xj : xu;
        if (v < R1B) s += bm;
        dst[(size_t)(r0 + (v & (R1B - 1))) * F + o] = s;
    }
}

// ---------------------------------------------------------------------------
// Kernel 2 (512 blocks x 512 threads): per 4 node rows
//   - wave (r,half) gathers its half of row r's neighbor list (float2 lanes)
//   - agg combine -> update GEMM (agg @ Wupd[F:2F], K split 4 ways)
//   - out = relu(xu + agg@Wupd2 + b_upd)
// ---------------------------------------------------------------------------
__global__ __launch_bounds__(512, 2) void k_agg(
    const int*   __restrict__ lstG,
    const int*   __restrict__ cntG,
    const float* __restrict__ xi,
    const float* __restrict__ xj,
    const float* __restrict__ xu,
    const float* __restrict__ Wupd,
    const float* __restrict__ bupd,
    float* __restrict__ out)
{
    __shared__ __align__(16) int   lst[R2B][LSTW];
    __shared__ int   cntp[R2B];
    __shared__ float aggP[8][F];
    __shared__ __align__(16) float agg[R2B][F];
    __shared__ float ps[4][R2B][F];

    const int t    = threadIdx.x;
    const int lane = t & 63;
    const int w    = t >> 6;            // wave 0..7
    const int q    = t >> 7;            // quarter 0..3
    const int o    = t & 127;
    const int r0   = blockIdx.x * R2B;
    const int b    = r0 >> 9;

    if (t < R2B) cntp[t] = cntG[r0 + t];
    __syncthreads();
    #pragma unroll
    for (int r = 0; r < R2B; ++r)
        for (int k = t; k < cntp[r]; k += 512)
            lst[r][k] = lstG[(size_t)(r0 + r) * LSTW + k];
    __syncthreads();

    // ---- gather: wave w -> row r = w>>1, half = w&1; lanes hold float2 cols
    {
        const int r = w >> 1, half = w & 1;
        const float* xjb = xj + (size_t)b * N_ * F;
        const float2 xir2 = *reinterpret_cast<const float2*>(
            &xi[(size_t)(r0 + r) * F + 2 * lane]);
        float2 acc = {0.f, 0.f};
        const int np = cntp[r];
        for (int k = half * 4; k < np; k += 8) {
            const int4 j4 = *reinterpret_cast<const int4*>(&lst[r][k]);
            const float2 v0 = *reinterpret_cast<const float2*>(&xjb[(size_t)j4.x * F + 2 * lane]);
            const float2 v1 = *reinterpret_cast<const float2*>(&xjb[(size_t)j4.y * F + 2 * lane]);
            const float2 v2 = *reinterpret_cast<const float2*>(&xjb[(size_t)j4.z * F + 2 * lane]);
            const float2 v3 = *reinterpret_cast<const float2*>(&xjb[(size_t)j4.w * F + 2 * lane]);
            acc.x += fmaxf(xir2.x + v0.x, 0.f);  acc.y += fmaxf(xir2.y + v0.y, 0.f);
            acc.x += fmaxf(xir2.x + v1.x, 0.f);  acc.y += fmaxf(xir2.y + v1.y, 0.f);
            acc.x += fmaxf(xir2.x + v2.x, 0.f);  acc.y += fmaxf(xir2.y + v2.y, 0.f);
            acc.x += fmaxf(xir2.x + v3.x, 0.f);  acc.y += fmaxf(xir2.y + v3.y, 0.f);
        }
        *reinterpret_cast<float2*>(&aggP[w][2 * lane]) = acc;
    }
    __syncthreads();
    agg[q][o] = aggP[2 * q][o] + aggP[2 * q + 1][o];   // q == row here
    __syncthreads();

    // ---- update GEMM: res = agg @ Wupd[F:2F], quarter q = 32 k's
    float res[R2B] = {0.f, 0.f, 0.f, 0.f};
    const int kb = q * 32;
    #pragma unroll
    for (int k = 0; k < 32; k += 4) {
        float4 av[R2B];
        #pragma unroll
        for (int r = 0; r < R2B; ++r)
            av[r] = *reinterpret_cast<const float4*>(&agg[r][kb + k]);
        #pragma unroll
        for (int u = 0; u < 4; ++u) {
            const float wv = Wupd[(size_t)(F + kb + k + u) * F + o];
            #pragma unroll
            for (int r = 0; r < R2B; ++r)
                res[r] = fmaf(reinterpret_cast<const float*>(&av[r])[u], wv, res[r]);
        }
    }
    #pragma unroll
    for (int r = 0; r < R2B; ++r) ps[q][r][o] = res[r];
    __syncthreads();

    if (q == 0) {
        const float bu = bupd[o];
        #pragma unroll
        for (int r = 0; r < R2B; ++r) {
            const float s = ps[0][r][o] + ps[1][r][o] + ps[2][r][o] + ps[3][r][o]
                          + xu[(size_t)(r0 + r) * F + o] + bu;
            out[(size_t)(r0 + r) * F + o] = fmaxf(s, 0.f);
        }
    }
}

// ---------------------------------------------------------------------------
extern "C" void kernel_launch(void* const* d_in, const int* in_sizes, int n_in,
                              void* d_out, int out_size, void* d_ws, size_t ws_size,
                              hipStream_t stream)
{
    const float* x    = (const float*)d_in[0];
    const float* adj  = (const float*)d_in[1];
    const float* Wmsg = (const float*)d_in[2];
    const float* bmsg = (const float*)d_in[3];
    const float* Wupd = (const float*)d_in[4];
    const float* bupd = (const float*)d_in[5];
    float* out = (float*)d_out;

    const size_t rows = (size_t)B_ * N_;               // 2048
    float* xi   = (float*)d_ws;                        // rows*F
    float* xj   = xi + rows * F;                       // rows*F + 1 sentinel row
    float* xu   = xj + (rows + 1) * F;                 // rows*F
    int*   lstG = (int*)(xu + rows * F);               // rows*LSTW
    int*   cntG = lstG + rows * LSTW;                  // rows

    k_pre<<<dim3(rows / R1B), dim3(512), 0, stream>>>(
        x, adj, Wmsg, bmsg, Wupd, xi, xj, xu, lstG, cntG);
    k_agg<<<dim3(rows / R2B), dim3(512), 0, stream>>>(
        lstG, cntG, xi, xj, xu, Wupd, bupd, out);
}